// Round 6
// baseline (320.137 us; speedup 1.0000x reference)
//
#include <hip/hip_runtime.h>
#include <hip/hip_cooperative_groups.h>
#include <math.h>

#define B 4
#define N 4096
#define M 8192
#define C 64
#define NB 1024
#define XMIN (-64.0f)
#define INV_BW 8.0f    // bucket width 0.125
#define CUT 15.0f      // truncation at exp(-15): err ~1e-4 << 0.43 threshold
#define QG 16          // queries per group (bucket-sorted)
#define PCH 64         // points staged per chunk
#define GRID (B * (N / QG))   // 1024 blocks

namespace cg = cooperative_groups;

__device__ __forceinline__ int bucket_of(float v) {
    int k = (int)floorf((v - XMIN) * INV_BW);
    return min(max(k, 0), NB - 1);
}

// Single cooperative kernel: bin -> permute -> gather with 2 grid syncs.
__global__ __launch_bounds__(256, 4) void fused_kernel(
    const float* __restrict__ xz, const float* __restrict__ z,
    const float* __restrict__ x,  const float* __restrict__ log_scale,
    int* __restrict__ bucket_start,   // [B][NB+1]
    int* __restrict__ runp,           // [B][NB] running point slots
    float* __restrict__ xs,           // [B*M + slack] sorted point coords
    float* __restrict__ zs,           // [B*M + slack][C] sorted z rows
    float* __restrict__ qcs,          // [B][N] sorted query coords
    int* __restrict__ qis,            // [B][N] sorted slot -> n
    float* __restrict__ out)          // [B][N][C]
{
    cg::grid_group grid = cg::this_grid();
    __shared__ __align__(16) char smem[20608];

    const int t    = threadIdx.x;
    const int lane = t & 63;
    const int w    = t >> 6;

    // ---------------- Phase A: per-batch binning (blocks 0..7) -------------
    if (blockIdx.x < 8) {
        int* hist = (int*)smem;                 // [NB]
        int* run  = (int*)(smem + 4096);        // [NB]
        int* wtot = (int*)(smem + 8192);        // [4]
        const bool isQ = blockIdx.x >= 4;
        const int  b   = blockIdx.x & 3;

        #pragma unroll
        for (int j = 0; j < 4; ++j) hist[t * 4 + j] = 0;
        __syncthreads();

        if (!isQ) {
            for (int j = 0; j < 32; ++j)
                atomicAdd(&hist[bucket_of(xz[b * M + j * 256 + t])], 1);
        } else {
            for (int j = 0; j < 16; ++j)
                atomicAdd(&hist[bucket_of(x[b * N + j * 256 + t])], 1);
        }
        __syncthreads();

        // scan: thread owns buckets [4t,4t+4); wave shuffle-scan of sums
        const int k0 = t * 4;
        int h0 = hist[k0], h1 = hist[k0 + 1], h2 = hist[k0 + 2], h3 = hist[k0 + 3];
        int tot = h0 + h1 + h2 + h3;
        int s = tot;
        #pragma unroll
        for (int off = 1; off < 64; off <<= 1) {
            int up = __shfl_up(s, off, 64);
            if (lane >= off) s += up;
        }
        if (lane == 63) wtot[w] = s;
        __syncthreads();
        int woff = 0;
        for (int i = 0; i < w; ++i) woff += wtot[i];
        const int excl = woff + s - tot;        // exclusive start of bucket k0

        if (!isQ) {
            bucket_start[b * (NB + 1) + k0 + 0] = excl;
            bucket_start[b * (NB + 1) + k0 + 1] = excl + h0;
            bucket_start[b * (NB + 1) + k0 + 2] = excl + h0 + h1;
            bucket_start[b * (NB + 1) + k0 + 3] = excl + h0 + h1 + h2;
            runp[b * NB + k0 + 0] = excl;
            runp[b * NB + k0 + 1] = excl + h0;
            runp[b * NB + k0 + 2] = excl + h0 + h1;
            runp[b * NB + k0 + 3] = excl + h0 + h1 + h2;
            if (t == 255) bucket_start[b * (NB + 1) + NB] = woff + s;  // == M
        } else {
            run[k0 + 0] = excl;
            run[k0 + 1] = excl + h0;
            run[k0 + 2] = excl + h0 + h1;
            run[k0 + 3] = excl + h0 + h1 + h2;
            __syncthreads();
            for (int j = 0; j < 16; ++j) {      // scatter queries
                int n = j * 256 + t;
                float v = x[b * N + n];
                int slot = atomicAdd(&run[bucket_of(v)], 1);
                qcs[b * N + slot] = v;
                qis[b * N + slot] = n;
            }
        }
    }

    grid.sync();

    // ------- Phase B: fused transpose+scatter of z (blocks 0..511) ---------
    if (blockIdx.x < 512) {
        float (*tile)[65] = (float(*)[65])smem;     // [64][65] padded
        int* slot = (int*)(smem + 16640);           // [64]
        const int b  = blockIdx.x >> 7;             // 128 tiles per batch
        const int m0 = (blockIdx.x & 127) * 64;

        // load 64x64 tile: lane = m (coalesced), 16 channel rows per thread
        #pragma unroll
        for (int cc = 0; cc < 16; ++cc) {
            int c = cc * 4 + w;
            tile[lane][c] = z[((size_t)b * C + c) * M + m0 + lane];  // [m][c], conflict-free
        }
        if (t < 64) {
            float v = xz[b * M + m0 + t];
            int s = atomicAdd(&runp[b * NB + bucket_of(v)], 1);
            slot[t] = s;
            xs[b * M + s] = v;
        }
        __syncthreads();
        // write rows: thread -> (local point j, float4 chunk c4); 4 rows/thread
        const int c4 = t & 15;
        #pragma unroll
        for (int jj = 0; jj < 4; ++jj) {
            int j = jj * 16 + (t >> 4);
            float4 v4 = make_float4(tile[j][c4 * 4 + 0], tile[j][c4 * 4 + 1],
                                    tile[j][c4 * 4 + 2], tile[j][c4 * 4 + 3]);
            ((float4*)zs)[((size_t)b * M + slot[j]) * 16 + c4] = v4;
        }
    }

    grid.sync();

    // ---------------- Phase C: gather (all 1024 blocks) --------------------
    {
        float (*zr)[C]   = (float(*)[C])smem;            // 16 KB
        float (*wl)[PCH] = (float(*)[PCH])(smem + 16384); // 4 KB
        float* qc = (float*)(smem + 20480);               // [QG]
        int*   qi = (int*)(smem + 20480 + 64);            // [QG]

        const int g  = blockIdx.x;
        const int b  = g >> 8;              // 256 groups per batch
        const int g0 = (g & 255) * QG;

        const float ls   = log_scale[0];
        const float coef = -0.5f * __expf(-2.0f * ls);   // negative
        const float R    = sqrtf(CUT / (-coef));

        if (t < QG) {
            qc[t] = qcs[b * N + g0 + t];
            qi[t] = qis[b * N + g0 + t];
        }
        __syncthreads();

        float xmin = qc[0], xmax = qc[0];
        #pragma unroll
        for (int j = 1; j < QG; ++j) {
            xmin = fminf(xmin, qc[j]);
            xmax = fmaxf(xmax, qc[j]);
        }
        const int s0 = bucket_start[b * (NB + 1) + bucket_of(xmin - R)];
        const int s1 = bucket_start[b * (NB + 1) + bucket_of(xmax + R) + 1];

        const float q0 = qc[w * 4 + 0], q1 = qc[w * 4 + 1];
        const float q2 = qc[w * 4 + 2], q3 = qc[w * 4 + 3];
        float a0 = 0.f, a1 = 0.f, a2 = 0.f, a3 = 0.f;

        const float*  xsb = xs + b * M;
        const float4* zs4 = (const float4*)zs + (size_t)b * M * 16;

        for (int cs = s0; cs < s1; cs += PCH) {
            const int cnt = min(PCH, s1 - cs);
            __syncthreads();                 // zr/wl free from previous chunk
            #pragma unroll
            for (int r = 0; r < 4; ++r) {    // 64 contiguous rows -> LDS
                const float4* gp = zs4 + ((size_t)cs) * 16 + r * 256 + w * 64 + lane;
                float* lp = &zr[r * 16 + w * 4][0];       // wave-uniform base
                __builtin_amdgcn_global_load_lds(
                    (const __attribute__((address_space(1))) void*)gp,
                    (__attribute__((address_space(3))) void*)lp, 16, 0, 0);
            }
            // overlapped: wave-local weights, lanes = points
            {
                const float pcr   = xsb[cs + lane];       // slack-backed
                const bool  valid = (cs + lane) < s1;
                float d0 = q0 - pcr, d1 = q1 - pcr, d2 = q2 - pcr, d3 = q3 - pcr;
                wl[w * 4 + 0][lane] = valid ? __expf(coef * d0 * d0) : 0.0f;
                wl[w * 4 + 1][lane] = valid ? __expf(coef * d1 * d1) : 0.0f;
                wl[w * 4 + 2][lane] = valid ? __expf(coef * d2 * d2) : 0.0f;
                wl[w * 4 + 3][lane] = valid ? __expf(coef * d3 * d3) : 0.0f;
            }
            __syncthreads();                 // zr staged (barrier drains vmcnt)
            for (int p = 0; p < cnt; p += 4) {
                float zv0 = zr[p + 0][lane];
                float zv1 = zr[p + 1][lane];
                float zv2 = zr[p + 2][lane];
                float zv3 = zr[p + 3][lane];
                const float4 wa = *(const float4*)&wl[w * 4 + 0][p];
                const float4 wb = *(const float4*)&wl[w * 4 + 1][p];
                const float4 wc = *(const float4*)&wl[w * 4 + 2][p];
                const float4 wd = *(const float4*)&wl[w * 4 + 3][p];
                a0 = fmaf(wa.x, zv0, a0); a0 = fmaf(wa.y, zv1, a0);
                a0 = fmaf(wa.z, zv2, a0); a0 = fmaf(wa.w, zv3, a0);
                a1 = fmaf(wb.x, zv0, a1); a1 = fmaf(wb.y, zv1, a1);
                a1 = fmaf(wb.z, zv2, a1); a1 = fmaf(wb.w, zv3, a1);
                a2 = fmaf(wc.x, zv0, a2); a2 = fmaf(wc.y, zv1, a2);
                a2 = fmaf(wc.z, zv2, a2); a2 = fmaf(wc.w, zv3, a2);
                a3 = fmaf(wd.x, zv0, a3); a3 = fmaf(wd.y, zv1, a3);
                a3 = fmaf(wd.z, zv2, a3); a3 = fmaf(wd.w, zv3, a3);
            }
        }

        out[((size_t)b * N + qi[w * 4 + 0]) * C + lane] = a0;
        out[((size_t)b * N + qi[w * 4 + 1]) * C + lane] = a1;
        out[((size_t)b * N + qi[w * 4 + 2]) * C + lane] = a2;
        out[((size_t)b * N + qi[w * 4 + 3]) * C + lane] = a3;
    }
}

extern "C" void kernel_launch(void* const* d_in, const int* in_sizes, int n_in,
                              void* d_out, int out_size, void* d_ws, size_t ws_size,
                              hipStream_t stream) {
    const float* xz = (const float*)d_in[0];  // [B,M,1]
    const float* z  = (const float*)d_in[1];  // [B,C,M]
    const float* x  = (const float*)d_in[2];  // [B,N,1]
    const float* ls = (const float*)d_in[3];  // scalar
    float* out = (float*)d_out;               // [B,N,C]

    char* ws = (char*)d_ws;
    size_t off = 0;
    auto alloc = [&](size_t bytes) { void* p = ws + off; off += (bytes + 255) & ~size_t(255); return p; };

    // +64 rows / +64 floats of slack: gather's unguarded chunk-tail reads
    float* zs   = (float*)alloc(((size_t)B * M + 64) * C * sizeof(float));  // ~8.4 MB
    float* xs   = (float*)alloc(((size_t)B * M + 64) * sizeof(float));
    float* qcs  = (float*)alloc((size_t)B * N * sizeof(float));
    int*   qis  = (int*)alloc((size_t)B * N * sizeof(int));
    int*   bst  = (int*)alloc((size_t)B * (NB + 1) * sizeof(int));
    int*   runp = (int*)alloc((size_t)B * NB * sizeof(int));

    void* args[] = {(void*)&xz, (void*)&z, (void*)&x, (void*)&ls,
                    (void*)&bst, (void*)&runp, (void*)&xs, (void*)&zs,
                    (void*)&qcs, (void*)&qis, (void*)&out};
    hipLaunchCooperativeKernel((void*)fused_kernel, dim3(GRID), dim3(256),
                               args, 0, stream);
}

// Round 7
// 94.537 us; speedup vs baseline: 3.3864x; 3.3864x over previous
//
#include <hip/hip_runtime.h>
#include <math.h>

#define B 4
#define N 4096
#define M 8192
#define C 64
#define NB 2048
#define XMIN (-64.0f)
#define INV_BW 16.0f   // bucket width 0.0625
#define CUT 15.0f      // truncation at exp(-15): err ~1e-4 << 0.43 threshold
#define QG 16          // queries per group (bucket-sorted)
#define PCH 64         // points staged per chunk

__device__ __forceinline__ int bucket_of(float v) {
    int k = (int)floorf((v - XMIN) * INV_BW);
    return min(max(k, 0), NB - 1);
}

// Blocks 0..3: bin points (batch b). Blocks 4..7: bin queries (batch b).
// Blocks 8..519: transpose z [B,C,M] -> zt [B,M,C], one 64x64 tile each.
// 1024 threads. Wave-shuffle scan: 2 barriers instead of 20.
__global__ __launch_bounds__(1024) void prep_kernel(
    const float* __restrict__ xz, const float* __restrict__ z,
    const float* __restrict__ x,
    int* __restrict__ bucket_start,    // [B][NB+1] (points)
    float* __restrict__ xs,            // [B*M + slack] sorted point coords
    int* __restrict__ pidx,            // [B][M] sorted slot -> original m
    float* __restrict__ qcs,           // [B][N] sorted query coords
    int* __restrict__ qis,             // [B][N] sorted slot -> original n
    float* __restrict__ zt)            // [B][M][C]
{
    const int t    = threadIdx.x;
    const int lane = t & 63;
    const int w    = t >> 6;            // wave 0..15

    if (blockIdx.x < 8) {
        __shared__ int hist[NB];
        __shared__ int run[NB];
        __shared__ int wsum[16];
        const bool isQ = blockIdx.x >= 4;
        const int  b   = blockIdx.x & 3;
        const int  CNTN = isQ ? N : M;
        const int  PT   = CNTN / 1024;              // 4 or 8 per thread
        const float* src = isQ ? (x + b * N) : (xz + b * M);

        hist[t] = 0; hist[t + 1024] = 0;
        __syncthreads();

        float pv[8]; int pk[8];
        for (int j = 0; j < PT; ++j) {
            float v = src[j * 1024 + t];            // coalesced
            pv[j] = v; pk[j] = bucket_of(v);
            atomicAdd(&hist[pk[j]], 1);
        }
        __syncthreads();

        // thread owns buckets {2t, 2t+1}; wave-scan thread sums, then wave offsets
        const int h0 = hist[2 * t], h1 = hist[2 * t + 1];
        const int tot = h0 + h1;
        int s = tot;
        #pragma unroll
        for (int off = 1; off < 64; off <<= 1) {
            int up = __shfl_up(s, off, 64);
            if (lane >= off) s += up;
        }
        if (lane == 63) wsum[w] = s;
        __syncthreads();
        int woff = 0;
        for (int i = 0; i < w; ++i) woff += wsum[i];
        const int excl = woff + s - tot;            // exclusive start of bucket 2t

        run[2 * t]     = excl;
        run[2 * t + 1] = excl + h0;
        if (!isQ) {
            bucket_start[b * (NB + 1) + 2 * t]     = excl;
            bucket_start[b * (NB + 1) + 2 * t + 1] = excl + h0;
            if (t == 1023) bucket_start[b * (NB + 1) + NB] = woff + s;  // == M
        }
        __syncthreads();

        if (!isQ) {
            for (int j = 0; j < PT; ++j) {
                int slot = atomicAdd(&run[pk[j]], 1);
                xs[b * M + slot]   = pv[j];
                pidx[b * M + slot] = j * 1024 + t;
            }
        } else {
            for (int j = 0; j < PT; ++j) {
                int slot = atomicAdd(&run[pk[j]], 1);
                qcs[b * N + slot] = pv[j];
                qis[b * N + slot] = j * 1024 + t;
            }
        }
    } else {
        const int tb = blockIdx.x - 8;
        const int b  = tb >> 7;            // M/64 = 128 tiles per batch
        const int m0 = (tb & 127) * 64;
        __shared__ float tile[64][65];
        const int m = t & 63;
        for (int c = t >> 6; c < 64; c += 16)
            tile[c][m] = z[((size_t)b * C + c) * M + m0 + m];   // coalesced in m
        __syncthreads();
        const int cc = t & 63;
        for (int mm = t >> 6; mm < 64; mm += 16)
            zt[((size_t)b * M + m0 + mm) * C + cc] = tile[cc][mm];  // coalesced in c
    }
}

// One block per group of QG=16 sorted queries; 4 waves, each owns 4 queries.
// Weights lane-parallel (lanes=points); zt rows staged direct-to-LDS via
// gathered global_load_lds (16B/lane); dot phase pure fmac. (Round-4 proven.)
__global__ __launch_bounds__(256) void gather_kernel(
    const float* __restrict__ log_scale,
    const int* __restrict__ bucket_start,
    const float* __restrict__ xs,
    const int* __restrict__ pidx,
    const float* __restrict__ qcs,
    const int* __restrict__ qis,
    const float* __restrict__ zt,      // [B][M][C]
    float* __restrict__ out)           // [B][N][C]
{
    const int t    = threadIdx.x;
    const int lane = t & 63;
    const int w    = t >> 6;            // wave 0..3
    const int g  = blockIdx.x;
    const int b  = g >> 8;              // N/QG = 256 groups per batch
    const int g0 = (g & 255) * QG;

    __shared__ __align__(16) float zr[PCH][C];    // 16 KB staged z rows
    __shared__ __align__(16) float wl[QG][PCH];   // 4 KB weights [q][p]
    __shared__ int   pr[PCH];                     // staged pidx chunk
    __shared__ float pcs[PCH];                    // staged point coords
    __shared__ float qc[QG];
    __shared__ int   qi[QG];

    const float ls   = log_scale[0];
    const float coef = -0.5f * __expf(-2.0f * ls);   // negative
    const float R    = sqrtf(CUT / (-coef));

    if (t < QG) {
        qc[t] = qcs[b * N + g0 + t];
        qi[t] = qis[b * N + g0 + t];
    }
    __syncthreads();

    float xmin = qc[0], xmax = qc[0];
    #pragma unroll
    for (int j = 1; j < QG; ++j) {
        xmin = fminf(xmin, qc[j]);
        xmax = fmaxf(xmax, qc[j]);
    }
    const int s0 = bucket_start[b * (NB + 1) + bucket_of(xmin - R)];
    const int s1 = bucket_start[b * (NB + 1) + bucket_of(xmax + R) + 1];

    const float q0 = qc[w * 4 + 0], q1 = qc[w * 4 + 1];
    const float q2 = qc[w * 4 + 2], q3 = qc[w * 4 + 3];

    if (s0 >= s1) {   // empty window (block-uniform): write zeros
        out[((size_t)b * N + qi[w * 4 + 0]) * C + lane] = 0.0f;
        out[((size_t)b * N + qi[w * 4 + 1]) * C + lane] = 0.0f;
        out[((size_t)b * N + qi[w * 4 + 2]) * C + lane] = 0.0f;
        out[((size_t)b * N + qi[w * 4 + 3]) * C + lane] = 0.0f;
        return;
    }

    float a0 = 0.f, a1 = 0.f, a2 = 0.f, a3 = 0.f;

    const float*  xsb = xs   + b * M;
    const int*    pib = pidx + b * M;
    const float4* zt4 = (const float4*)(zt + (size_t)b * M * C);

    for (int cs = s0; cs < s1; cs += PCH) {
        const int cnt = min(PCH, s1 - cs);
        __syncthreads();                 // zr/pr free from previous chunk
        if (t < PCH) {
            int row = min(cs + t, s1 - 1);
            pr[t]  = pib[row];
            pcs[t] = xsb[row];
        }
        __syncthreads();                 // pr/pcs ready
        // stage zt rows -> zr via global_load_lds (lane-contiguous LDS dest)
        #pragma unroll
        for (int i = 0; i < 4; ++i) {
            const int r = i * 16 + w * 4 + (lane >> 4);   // local row 0..63
            const float4* gp = zt4 + (size_t)pr[r] * 16 + (lane & 15);
            float* lp = &zr[i * 16 + w * 4][0];            // wave-uniform base
            __builtin_amdgcn_global_load_lds(
                (const __attribute__((address_space(1))) void*)gp,
                (__attribute__((address_space(3))) void*)lp, 16, 0, 0);
        }
        // overlapped: wave-local weights, lanes = points
        {
            const float pcr   = pcs[lane];
            const bool  valid = (cs + lane) < s1;
            float d0 = q0 - pcr, d1 = q1 - pcr, d2 = q2 - pcr, d3 = q3 - pcr;
            wl[w * 4 + 0][lane] = valid ? __expf(coef * d0 * d0) : 0.0f;
            wl[w * 4 + 1][lane] = valid ? __expf(coef * d1 * d1) : 0.0f;
            wl[w * 4 + 2][lane] = valid ? __expf(coef * d2 * d2) : 0.0f;
            wl[w * 4 + 3][lane] = valid ? __expf(coef * d3 * d3) : 0.0f;
        }
        __syncthreads();                 // zr staged (barrier drains vmcnt)
        for (int p = 0; p < cnt; p += 4) {
            float zv0 = zr[p + 0][lane];
            float zv1 = zr[p + 1][lane];
            float zv2 = zr[p + 2][lane];
            float zv3 = zr[p + 3][lane];
            const float4 wa = *(const float4*)&wl[w * 4 + 0][p];
            const float4 wb = *(const float4*)&wl[w * 4 + 1][p];
            const float4 wc = *(const float4*)&wl[w * 4 + 2][p];
            const float4 wd = *(const float4*)&wl[w * 4 + 3][p];
            a0 = fmaf(wa.x, zv0, a0); a0 = fmaf(wa.y, zv1, a0);
            a0 = fmaf(wa.z, zv2, a0); a0 = fmaf(wa.w, zv3, a0);
            a1 = fmaf(wb.x, zv0, a1); a1 = fmaf(wb.y, zv1, a1);
            a1 = fmaf(wb.z, zv2, a1); a1 = fmaf(wb.w, zv3, a1);
            a2 = fmaf(wc.x, zv0, a2); a2 = fmaf(wc.y, zv1, a2);
            a2 = fmaf(wc.z, zv2, a2); a2 = fmaf(wc.w, zv3, a2);
            a3 = fmaf(wd.x, zv0, a3); a3 = fmaf(wd.y, zv1, a3);
            a3 = fmaf(wd.z, zv2, a3); a3 = fmaf(wd.w, zv3, a3);
        }
    }

    out[((size_t)b * N + qi[w * 4 + 0]) * C + lane] = a0;
    out[((size_t)b * N + qi[w * 4 + 1]) * C + lane] = a1;
    out[((size_t)b * N + qi[w * 4 + 2]) * C + lane] = a2;
    out[((size_t)b * N + qi[w * 4 + 3]) * C + lane] = a3;
}

extern "C" void kernel_launch(void* const* d_in, const int* in_sizes, int n_in,
                              void* d_out, int out_size, void* d_ws, size_t ws_size,
                              hipStream_t stream) {
    const float* xz = (const float*)d_in[0];  // [B,M,1]
    const float* z  = (const float*)d_in[1];  // [B,C,M]
    const float* x  = (const float*)d_in[2];  // [B,N,1]
    const float* ls = (const float*)d_in[3];  // scalar
    float* out = (float*)d_out;               // [B,N,C]

    char* ws = (char*)d_ws;
    size_t off = 0;
    auto alloc = [&](size_t bytes) { void* p = ws + off; off += (bytes + 255) & ~size_t(255); return p; };

    float* zt   = (float*)alloc((size_t)B * M * C * sizeof(float));       // 8 MB
    float* xs   = (float*)alloc(((size_t)B * M + 64) * sizeof(float));
    int*   pidx = (int*)alloc((size_t)B * M * sizeof(int));
    float* qcs  = (float*)alloc((size_t)B * N * sizeof(float));
    int*   qis  = (int*)alloc((size_t)B * N * sizeof(int));
    int*   bst  = (int*)alloc((size_t)B * (NB + 1) * sizeof(int));

    prep_kernel<<<8 + B * M / 64, 1024, 0, stream>>>(xz, z, x, bst, xs, pidx, qcs, qis, zt);
    gather_kernel<<<B * (N / QG), 256, 0, stream>>>(ls, bst, xs, pidx, qcs, qis, zt, out);
}

// Round 8
// 92.324 us; speedup vs baseline: 3.4675x; 1.0240x over previous
//
#include <hip/hip_runtime.h>
#include <math.h>

#define B 4
#define N 4096
#define M 8192
#define C 64
#define NB 2048
#define XMIN (-64.0f)
#define INV_BW 16.0f   // bucket width 0.0625
#define CUT 8.0f       // truncation at exp(-8): worst-case err ~0.008 << 0.43
#define QG 16          // queries per group (bucket-sorted)
#define PCH 64         // points staged per chunk

__device__ __forceinline__ int bucket_of(float v) {
    int k = (int)floorf((v - XMIN) * INV_BW);
    return min(max(k, 0), NB - 1);
}

// Blocks 0..3: bin points (batch b) -> bucket_start, xs (sorted coords),
//              islot[m] = sorted slot of original point m.
// Blocks 4..7: bin queries (batch b) -> qcs/qis (sorted).
// Wave-shuffle scan: 2 barriers.
__global__ __launch_bounds__(1024) void bin_kernel(
    const float* __restrict__ xz, const float* __restrict__ x,
    int* __restrict__ bucket_start,    // [B][NB+1] (points)
    float* __restrict__ xs,            // [B*M + slack] sorted point coords
    int* __restrict__ islot,           // [B][M] original m -> sorted slot
    float* __restrict__ qcs,           // [B][N] sorted query coords
    int* __restrict__ qis)             // [B][N] sorted slot -> original n
{
    const int t    = threadIdx.x;
    const int lane = t & 63;
    const int w    = t >> 6;            // wave 0..15

    __shared__ int hist[NB];
    __shared__ int run[NB];
    __shared__ int wsum[16];
    const bool isQ = blockIdx.x >= 4;
    const int  b   = blockIdx.x & 3;
    const int  PT  = isQ ? (N / 1024) : (M / 1024);   // 4 or 8
    const float* src = isQ ? (x + b * N) : (xz + b * M);

    hist[t] = 0; hist[t + 1024] = 0;
    __syncthreads();

    float pv[8]; int pk[8];
    for (int j = 0; j < PT; ++j) {
        float v = src[j * 1024 + t];            // coalesced
        pv[j] = v; pk[j] = bucket_of(v);
        atomicAdd(&hist[pk[j]], 1);
    }
    __syncthreads();

    // thread owns buckets {2t, 2t+1}; wave shuffle-scan + wave offsets
    const int h0 = hist[2 * t], h1 = hist[2 * t + 1];
    const int tot = h0 + h1;
    int s = tot;
    #pragma unroll
    for (int off = 1; off < 64; off <<= 1) {
        int up = __shfl_up(s, off, 64);
        if (lane >= off) s += up;
    }
    if (lane == 63) wsum[w] = s;
    __syncthreads();
    int woff = 0;
    for (int i = 0; i < w; ++i) woff += wsum[i];
    const int excl = woff + s - tot;            // exclusive start of bucket 2t

    run[2 * t]     = excl;
    run[2 * t + 1] = excl + h0;
    if (!isQ) {
        bucket_start[b * (NB + 1) + 2 * t]     = excl;
        bucket_start[b * (NB + 1) + 2 * t + 1] = excl + h0;
        if (t == 1023) bucket_start[b * (NB + 1) + NB] = woff + s;  // == M
    }
    __syncthreads();

    if (!isQ) {
        for (int j = 0; j < PT; ++j) {
            int slot = atomicAdd(&run[pk[j]], 1);
            xs[b * M + slot]           = pv[j];
            islot[b * M + j * 1024 + t] = slot;      // coalesced write
        }
    } else {
        for (int j = 0; j < PT; ++j) {
            int slot = atomicAdd(&run[pk[j]], 1);
            qcs[b * N + slot] = pv[j];
            qis[b * N + slot] = j * 1024 + t;
        }
    }
}

// 512 blocks: permute z [B,C,M] into sorted-row layout zs[slot][C].
// No atomics: slot comes from islot. LDS tile transpose, conflict-free.
__global__ __launch_bounds__(1024) void permz_kernel(
    const float* __restrict__ z, const int* __restrict__ islot,
    float* __restrict__ zs)            // [B*M + slack][C]
{
    const int t  = threadIdx.x;
    const int b  = blockIdx.x >> 7;            // 128 tiles per batch
    const int m0 = (blockIdx.x & 127) * 64;
    __shared__ float tile[64][65];
    __shared__ int slot_s[64];

    const int m = t & 63;
    #pragma unroll
    for (int k = 0; k < 4; ++k) {
        int c = (t >> 6) + 16 * k;
        tile[c][m] = z[((size_t)b * C + c) * M + m0 + m];   // coalesced in m
    }
    if (t < 64) slot_s[t] = islot[b * M + m0 + t];
    __syncthreads();

    // one float4 store per thread: row j (local), chunk c4
    const int j  = t >> 4;       // 0..63
    const int c4 = t & 15;
    float4 v4 = make_float4(tile[c4 * 4 + 0][j], tile[c4 * 4 + 1][j],
                            tile[c4 * 4 + 2][j], tile[c4 * 4 + 3][j]);
    ((float4*)zs)[((size_t)b * M + slot_s[j]) * 16 + c4] = v4;
}

// One block per group of QG=16 sorted queries; 4 waves, each owns 4 queries.
// Window is a CONTIGUOUS slot range: zs rows stream direct-to-LDS via
// coalesced global_load_lds; weights lane-parallel, overlapped with staging.
__global__ __launch_bounds__(256) void gather_kernel(
    const float* __restrict__ log_scale,
    const int* __restrict__ bucket_start,
    const float* __restrict__ xs,
    const float* __restrict__ qcs,
    const int* __restrict__ qis,
    const float* __restrict__ zs,      // [B*M + slack][C] sorted rows
    float* __restrict__ out)           // [B][N][C]
{
    const int t    = threadIdx.x;
    const int lane = t & 63;
    const int w    = t >> 6;            // wave 0..3
    const int g  = blockIdx.x;
    const int b  = g >> 8;              // 256 groups per batch
    const int g0 = (g & 255) * QG;

    __shared__ __align__(16) float zr[PCH][C];    // 16 KB staged z rows
    __shared__ __align__(16) float wl[QG][PCH];   // 4 KB weights [q][p]
    __shared__ float qc[QG];
    __shared__ int   qi[QG];

    const float ls   = log_scale[0];
    const float coef = -0.5f * __expf(-2.0f * ls);   // negative
    const float R    = sqrtf(CUT / (-coef));

    if (t < QG) {
        qc[t] = qcs[b * N + g0 + t];
        qi[t] = qis[b * N + g0 + t];
    }
    __syncthreads();

    float xmin = qc[0], xmax = qc[0];
    #pragma unroll
    for (int j = 1; j < QG; ++j) {
        xmin = fminf(xmin, qc[j]);
        xmax = fmaxf(xmax, qc[j]);
    }
    const int s0 = bucket_start[b * (NB + 1) + bucket_of(xmin - R)];
    const int s1 = bucket_start[b * (NB + 1) + bucket_of(xmax + R) + 1];

    const float q0 = qc[w * 4 + 0], q1 = qc[w * 4 + 1];
    const float q2 = qc[w * 4 + 2], q3 = qc[w * 4 + 3];

    if (s0 >= s1) {   // empty window (block-uniform): write zeros
        out[((size_t)b * N + qi[w * 4 + 0]) * C + lane] = 0.0f;
        out[((size_t)b * N + qi[w * 4 + 1]) * C + lane] = 0.0f;
        out[((size_t)b * N + qi[w * 4 + 2]) * C + lane] = 0.0f;
        out[((size_t)b * N + qi[w * 4 + 3]) * C + lane] = 0.0f;
        return;
    }

    float a0 = 0.f, a1 = 0.f, a2 = 0.f, a3 = 0.f;

    const float*  xsb = xs + b * M;
    const float4* zs4 = (const float4*)zs + (size_t)b * M * 16;

    for (int cs = s0; cs < s1; cs += PCH) {
        const int cnt = min(PCH, s1 - cs);
        __syncthreads();                 // zr/wl free from previous chunk
        // stage 64 contiguous rows -> zr: wave w round r covers local rows
        // r*16+w*4 .. +3; lane supplies 16B; fully-coalesced 4KB per instr.
        #pragma unroll
        for (int r = 0; r < 4; ++r) {
            const float4* gp = zs4 + ((size_t)cs) * 16 + r * 256 + w * 64 + lane;
            float* lp = &zr[r * 16 + w * 4][0];       // wave-uniform base
            __builtin_amdgcn_global_load_lds(
                (const __attribute__((address_space(1))) void*)gp,
                (__attribute__((address_space(3))) void*)lp, 16, 0, 0);
        }
        // overlapped: wave-local weights, lanes = points (coords straight
        // from global, wave-coalesced 256B, L1/L2-hot; slack-backed)
        {
            const float pcr   = xsb[cs + lane];
            const bool  valid = (cs + lane) < s1;
            float d0 = q0 - pcr, d1 = q1 - pcr, d2 = q2 - pcr, d3 = q3 - pcr;
            wl[w * 4 + 0][lane] = valid ? __expf(coef * d0 * d0) : 0.0f;
            wl[w * 4 + 1][lane] = valid ? __expf(coef * d1 * d1) : 0.0f;
            wl[w * 4 + 2][lane] = valid ? __expf(coef * d2 * d2) : 0.0f;
            wl[w * 4 + 3][lane] = valid ? __expf(coef * d3 * d3) : 0.0f;
        }
        __syncthreads();                 // zr staged (barrier drains vmcnt)
        for (int p = 0; p < cnt; p += 4) {
            float zv0 = zr[p + 0][lane];
            float zv1 = zr[p + 1][lane];
            float zv2 = zr[p + 2][lane];
            float zv3 = zr[p + 3][lane];
            const float4 wa = *(const float4*)&wl[w * 4 + 0][p];
            const float4 wb = *(const float4*)&wl[w * 4 + 1][p];
            const float4 wc = *(const float4*)&wl[w * 4 + 2][p];
            const float4 wd = *(const float4*)&wl[w * 4 + 3][p];
            a0 = fmaf(wa.x, zv0, a0); a0 = fmaf(wa.y, zv1, a0);
            a0 = fmaf(wa.z, zv2, a0); a0 = fmaf(wa.w, zv3, a0);
            a1 = fmaf(wb.x, zv0, a1); a1 = fmaf(wb.y, zv1, a1);
            a1 = fmaf(wb.z, zv2, a1); a1 = fmaf(wb.w, zv3, a1);
            a2 = fmaf(wc.x, zv0, a2); a2 = fmaf(wc.y, zv1, a2);
            a2 = fmaf(wc.z, zv2, a2); a2 = fmaf(wc.w, zv3, a2);
            a3 = fmaf(wd.x, zv0, a3); a3 = fmaf(wd.y, zv1, a3);
            a3 = fmaf(wd.z, zv2, a3); a3 = fmaf(wd.w, zv3, a3);
        }
    }

    out[((size_t)b * N + qi[w * 4 + 0]) * C + lane] = a0;
    out[((size_t)b * N + qi[w * 4 + 1]) * C + lane] = a1;
    out[((size_t)b * N + qi[w * 4 + 2]) * C + lane] = a2;
    out[((size_t)b * N + qi[w * 4 + 3]) * C + lane] = a3;
}

extern "C" void kernel_launch(void* const* d_in, const int* in_sizes, int n_in,
                              void* d_out, int out_size, void* d_ws, size_t ws_size,
                              hipStream_t stream) {
    const float* xz = (const float*)d_in[0];  // [B,M,1]
    const float* z  = (const float*)d_in[1];  // [B,C,M]
    const float* x  = (const float*)d_in[2];  // [B,N,1]
    const float* ls = (const float*)d_in[3];  // scalar
    float* out = (float*)d_out;               // [B,N,C]

    char* ws = (char*)d_ws;
    size_t off = 0;
    auto alloc = [&](size_t bytes) { void* p = ws + off; off += (bytes + 255) & ~size_t(255); return p; };

    // +64 rows / +64 floats slack: gather's unguarded chunk-tail reads land in
    // ws (0xAA pattern is a finite float; masked by wl=0, so fma-safe).
    float* zs    = (float*)alloc(((size_t)B * M + 64) * C * sizeof(float));  // ~8.4 MB
    float* xs    = (float*)alloc(((size_t)B * M + 64) * sizeof(float));
    int*   islot = (int*)alloc((size_t)B * M * sizeof(int));
    float* qcs   = (float*)alloc((size_t)B * N * sizeof(float));
    int*   qis   = (int*)alloc((size_t)B * N * sizeof(int));
    int*   bst   = (int*)alloc((size_t)B * (NB + 1) * sizeof(int));

    bin_kernel<<<8, 1024, 0, stream>>>(xz, x, bst, xs, islot, qcs, qis);
    permz_kernel<<<512, 1024, 0, stream>>>(z, islot, zs);
    gather_kernel<<<B * (N / QG), 256, 0, stream>>>(ls, bst, xs, qcs, qis, zs, out);
}

// Round 9
// 89.424 us; speedup vs baseline: 3.5800x; 1.0324x over previous
//
#include <hip/hip_runtime.h>
#include <math.h>

#define B 4
#define N 4096
#define M 8192
#define C 64
#define NB 2048
#define XMIN (-64.0f)
#define INV_BW 16.0f   // bucket width 0.0625
#define CUT 10.0f      // truncation at exp(-10): err ~0.008 << 0.43
#define QG 16          // queries per group == MFMA M

typedef __attribute__((ext_vector_type(8))) short short8;   // 8 bf16
typedef __attribute__((ext_vector_type(4))) float f32x4;

__device__ __forceinline__ int bucket_of(float v) {
    int k = (int)floorf((v - XMIN) * INV_BW);
    return min(max(k, 0), NB - 1);
}

__device__ __forceinline__ unsigned short f2bf(float f) {   // RNE fp32->bf16
    unsigned int u = __float_as_uint(f);
    return (unsigned short)((u + 0x7FFF + ((u >> 16) & 1)) >> 16);
}

// Blocks 0..3: bin points (batch b) -> bucket_start, xs, islot.
// Blocks 4..7: bin queries (batch b) -> qcs/qis. Wave-shuffle scan.
__global__ __launch_bounds__(1024) void bin_kernel(
    const float* __restrict__ xz, const float* __restrict__ x,
    int* __restrict__ bucket_start,    // [B][NB+1]
    float* __restrict__ xs,            // [B*M + slack] sorted point coords
    int* __restrict__ islot,           // [B][M] original m -> sorted slot
    float* __restrict__ qcs,           // [B][N] sorted query coords
    int* __restrict__ qis)             // [B][N] sorted slot -> original n
{
    const int t    = threadIdx.x;
    const int lane = t & 63;
    const int w    = t >> 6;

    __shared__ int hist[NB];
    __shared__ int run[NB];
    __shared__ int wsum[16];
    const bool isQ = blockIdx.x >= 4;
    const int  b   = blockIdx.x & 3;
    const int  PT  = isQ ? (N / 1024) : (M / 1024);
    const float* src = isQ ? (x + b * N) : (xz + b * M);

    hist[t] = 0; hist[t + 1024] = 0;
    __syncthreads();

    float pv[8]; int pk[8];
    for (int j = 0; j < PT; ++j) {
        float v = src[j * 1024 + t];
        pv[j] = v; pk[j] = bucket_of(v);
        atomicAdd(&hist[pk[j]], 1);
    }
    __syncthreads();

    const int h0 = hist[2 * t], h1 = hist[2 * t + 1];
    const int tot = h0 + h1;
    int s = tot;
    #pragma unroll
    for (int off = 1; off < 64; off <<= 1) {
        int up = __shfl_up(s, off, 64);
        if (lane >= off) s += up;
    }
    if (lane == 63) wsum[w] = s;
    __syncthreads();
    int woff = 0;
    for (int i = 0; i < w; ++i) woff += wsum[i];
    const int excl = woff + s - tot;

    run[2 * t]     = excl;
    run[2 * t + 1] = excl + h0;
    if (!isQ) {
        bucket_start[b * (NB + 1) + 2 * t]     = excl;
        bucket_start[b * (NB + 1) + 2 * t + 1] = excl + h0;
        if (t == 1023) bucket_start[b * (NB + 1) + NB] = woff + s;  // == M
    }
    __syncthreads();

    if (!isQ) {
        for (int j = 0; j < PT; ++j) {
            int slot = atomicAdd(&run[pk[j]], 1);
            xs[b * M + slot]            = pv[j];
            islot[b * M + j * 1024 + t] = slot;
        }
    } else {
        for (int j = 0; j < PT; ++j) {
            int slot = atomicAdd(&run[pk[j]], 1);
            qcs[b * N + slot] = pv[j];
            qis[b * N + slot] = j * 1024 + t;
        }
    }
}

// 512 blocks: permute z [B,C,M] into bf16 sorted-row layout zs[slot][C].
__global__ __launch_bounds__(1024) void permz_kernel(
    const float* __restrict__ z, const int* __restrict__ islot,
    unsigned short* __restrict__ zs)   // [B*M + slack][C] bf16
{
    const int t  = threadIdx.x;
    const int b  = blockIdx.x >> 7;
    const int m0 = (blockIdx.x & 127) * 64;
    __shared__ float tile[64][65];
    __shared__ int slot_s[64];

    const int m = t & 63;
    #pragma unroll
    for (int k = 0; k < 4; ++k) {
        int c = (t >> 6) + 16 * k;
        tile[c][m] = z[((size_t)b * C + c) * M + m0 + m];   // coalesced in m
    }
    if (t < 64) slot_s[t] = islot[b * M + m0 + t];
    __syncthreads();

    // thread t -> local point j, 4-channel chunk c4: one ushort4 (8B) store
    const int j  = t >> 4;
    const int c4 = t & 15;
    ushort4 v4;
    v4.x = f2bf(tile[c4 * 4 + 0][j]);
    v4.y = f2bf(tile[c4 * 4 + 1][j]);
    v4.z = f2bf(tile[c4 * 4 + 2][j]);
    v4.w = f2bf(tile[c4 * 4 + 3][j]);
    ((ushort4*)zs)[((size_t)b * M + slot_s[j]) * 16 + c4] = v4;
}

// One block per 16 sorted queries; 4 waves, each computes the full 16 queries
// x its 16-channel slice via mfma_f32_16x16x32_bf16 (2 per 64-pt chunk).
// A = weights (computed in regs, bf16), B = staged zs rows (bf16 LDS).
__global__ __launch_bounds__(256) void gather_kernel(
    const float* __restrict__ log_scale,
    const int* __restrict__ bucket_start,
    const float* __restrict__ xs,
    const float* __restrict__ qcs,
    const int* __restrict__ qis,
    const unsigned short* __restrict__ zs,   // [B*M + slack][C] bf16
    float* __restrict__ out)                 // [B][N][C]
{
    const int t    = threadIdx.x;
    const int lane = t & 63;
    const int w    = t >> 6;            // wave 0..3 -> channels w*16..+15
    const int quad = lane >> 4;         // 0..3
    const int low4 = lane & 15;
    const int g  = blockIdx.x;
    const int b  = g >> 8;              // 256 groups per batch
    const int g0 = (g & 255) * QG;

    __shared__ unsigned short zr[64 * 64];   // 8 KB: 64 rows x 64 ch bf16
    __shared__ float qcS[QG];
    __shared__ int   qiS[QG];

    const float ls   = log_scale[0];
    const float coef = -0.5f * __expf(-2.0f * ls);   // negative
    const float R    = sqrtf(CUT / (-coef));

    if (t < QG) {
        qcS[t] = qcs[b * N + g0 + t];
        qiS[t] = qis[b * N + g0 + t];
    }
    __syncthreads();

    float xmin = qcS[0], xmax = qcS[0];
    #pragma unroll
    for (int j = 1; j < QG; ++j) {
        xmin = fminf(xmin, qcS[j]);
        xmax = fmaxf(xmax, qcS[j]);
    }
    const int s0 = bucket_start[b * (NB + 1) + bucket_of(xmin - R)];
    const int s1 = bucket_start[b * (NB + 1) + bucket_of(xmax + R) + 1];

    const float qv = qcS[low4];          // A-row m = lane&15 (this lane's query)
    f32x4 acc = {0.f, 0.f, 0.f, 0.f};

    const float* xsb = xs + b * M;
    const unsigned short* zsb = zs + (size_t)b * M * C;

    for (int cs = s0; cs < s1; cs += 64) {
        __syncthreads();                 // zr free from previous chunk
        // stage rows cs..cs+63 (128B bf16 rows): 2 global_load_lds per wave,
        // each 64 lanes x 16B = 1KB, lane-contiguous, fully coalesced.
        #pragma unroll
        for (int r = 0; r < 2; ++r) {
            const unsigned short* gp =
                zsb + ((size_t)cs + (w * 2 + r) * 8 + (lane >> 3)) * C + (lane & 7) * 8;
            unsigned short* lp = zr + (w * 2 + r) * 512;   // wave-uniform base
            __builtin_amdgcn_global_load_lds(
                (const __attribute__((address_space(1))) void*)gp,
                (__attribute__((address_space(3))) void*)lp, 16, 0, 0);
        }
        // A fragments (overlap the loads): lane -> query m=low4, k=quad*8+j
        short8 afrag[2];
        #pragma unroll
        for (int kh = 0; kh < 2; ++kh) {
            #pragma unroll
            for (int j = 0; j < 8; ++j) {
                const int k = kh * 32 + quad * 8 + j;
                const float xp = xsb[cs + k];      // L1-hot broadcast per quad
                const float d  = qv - xp;
                float wgt = __expf(coef * d * d);
                wgt = (cs + k < s1) ? wgt : 0.0f;  // mask chunk tail
                afrag[kh][j] = (short)f2bf(wgt);
            }
        }
        __syncthreads();                 // zr staged (barrier drains vmcnt)
        // B fragments + MFMA: B[k][n] n=low4 -> channel w*16+low4
        #pragma unroll
        for (int kh = 0; kh < 2; ++kh) {
            short8 bfrag;
            #pragma unroll
            for (int j = 0; j < 8; ++j) {
                const int p = kh * 32 + quad * 8 + j;
                bfrag[j] = (short)zr[p * 64 + w * 16 + low4];
            }
            acc = __builtin_amdgcn_mfma_f32_16x16x32_bf16(afrag[kh], bfrag, acc, 0, 0, 0);
        }
    }

    // D: row(query) = quad*4 + r, col(channel local) = low4
    #pragma unroll
    for (int r = 0; r < 4; ++r) {
        const int q = quad * 4 + r;
        out[((size_t)b * N + qiS[q]) * C + w * 16 + low4] = acc[r];
    }
}

extern "C" void kernel_launch(void* const* d_in, const int* in_sizes, int n_in,
                              void* d_out, int out_size, void* d_ws, size_t ws_size,
                              hipStream_t stream) {
    const float* xz = (const float*)d_in[0];  // [B,M,1]
    const float* z  = (const float*)d_in[1];  // [B,C,M]
    const float* x  = (const float*)d_in[2];  // [B,N,1]
    const float* ls = (const float*)d_in[3];  // scalar
    float* out = (float*)d_out;               // [B,N,C]

    char* ws = (char*)d_ws;
    size_t off = 0;
    auto alloc = [&](size_t bytes) { void* p = ws + off; off += (bytes + 255) & ~size_t(255); return p; };

    // slack rows/floats back the gather's unguarded chunk-tail reads (masked
    // by w=0; 0xAA bf16/f32 patterns are small finite values, fma-safe).
    unsigned short* zs = (unsigned short*)alloc(((size_t)B * M + 64) * C * sizeof(unsigned short)); // ~4.2MB
    float* xs    = (float*)alloc(((size_t)B * M + 64) * sizeof(float));
    int*   islot = (int*)alloc((size_t)B * M * sizeof(int));
    float* qcs   = (float*)alloc((size_t)B * N * sizeof(float));
    int*   qis   = (int*)alloc((size_t)B * N * sizeof(int));
    int*   bst   = (int*)alloc((size_t)B * (NB + 1) * sizeof(int));

    bin_kernel<<<8, 1024, 0, stream>>>(xz, x, bst, xs, islot, qcs, qis);
    permz_kernel<<<512, 1024, 0, stream>>>(z, islot, zs);
    gather_kernel<<<B * (N / QG), 256, 0, stream>>>(ls, bst, xs, qcs, qis, zs, out);
}

// Round 10
// 85.792 us; speedup vs baseline: 3.7316x; 1.0423x over previous
//
#include <hip/hip_runtime.h>
#include <math.h>

#define B 4
#define N 4096
#define M 8192
#define C 64
#define NB 2048
#define XMIN (-64.0f)
#define INV_BW 16.0f   // bucket width 0.0625
#define CUT 10.0f      // truncation at exp(-10): err ~0.008 << 0.43
#define QG 16          // queries per group == MFMA M

typedef __attribute__((ext_vector_type(8))) short short8;   // 8 bf16
typedef __attribute__((ext_vector_type(4))) float f32x4;

__device__ __forceinline__ int bucket_of(float v) {
    int k = (int)floorf((v - XMIN) * INV_BW);
    return min(max(k, 0), NB - 1);
}

__device__ __forceinline__ unsigned short f2bf(float f) {   // RNE fp32->bf16
    unsigned int u = __float_as_uint(f);
    return (unsigned short)((u + 0x7FFF + ((u >> 16) & 1)) >> 16);
}

// Blocks 0..3: bin points (batch b) -> bucket_start, xs, islot.
// Blocks 4..7: bin queries (batch b) -> qcs/qis. Wave-shuffle scan.
__global__ __launch_bounds__(1024) void bin_kernel(
    const float* __restrict__ xz, const float* __restrict__ x,
    int* __restrict__ bucket_start,    // [B][NB+1]
    float* __restrict__ xs,            // [B*M + slack] sorted point coords
    int* __restrict__ islot,           // [B][M] original m -> sorted slot
    float* __restrict__ qcs,           // [B][N] sorted query coords
    int* __restrict__ qis)             // [B][N] sorted slot -> original n
{
    const int t    = threadIdx.x;
    const int lane = t & 63;
    const int w    = t >> 6;

    __shared__ int hist[NB];
    __shared__ int run[NB];
    __shared__ int wsum[16];
    const bool isQ = blockIdx.x >= 4;
    const int  b   = blockIdx.x & 3;
    const int  PT  = isQ ? (N / 1024) : (M / 1024);
    const float* src = isQ ? (x + b * N) : (xz + b * M);

    hist[t] = 0; hist[t + 1024] = 0;
    __syncthreads();

    float pv[8]; int pk[8];
    for (int j = 0; j < PT; ++j) {
        float v = src[j * 1024 + t];
        pv[j] = v; pk[j] = bucket_of(v);
        atomicAdd(&hist[pk[j]], 1);
    }
    __syncthreads();

    const int h0 = hist[2 * t], h1 = hist[2 * t + 1];
    const int tot = h0 + h1;
    int s = tot;
    #pragma unroll
    for (int off = 1; off < 64; off <<= 1) {
        int up = __shfl_up(s, off, 64);
        if (lane >= off) s += up;
    }
    if (lane == 63) wsum[w] = s;
    __syncthreads();
    int woff = 0;
    for (int i = 0; i < w; ++i) woff += wsum[i];
    const int excl = woff + s - tot;

    run[2 * t]     = excl;
    run[2 * t + 1] = excl + h0;
    if (!isQ) {
        bucket_start[b * (NB + 1) + 2 * t]     = excl;
        bucket_start[b * (NB + 1) + 2 * t + 1] = excl + h0;
        if (t == 1023) bucket_start[b * (NB + 1) + NB] = woff + s;  // == M
    }
    __syncthreads();

    if (!isQ) {
        for (int j = 0; j < PT; ++j) {
            int slot = atomicAdd(&run[pk[j]], 1);
            xs[b * M + slot]            = pv[j];
            islot[b * M + j * 1024 + t] = slot;
        }
    } else {
        for (int j = 0; j < PT; ++j) {
            int slot = atomicAdd(&run[pk[j]], 1);
            qcs[b * N + slot] = pv[j];
            qis[b * N + slot] = j * 1024 + t;
        }
    }
}

// 512 blocks: permute z [B,C,M] into bf16 sorted-row layout zs[slot][C].
__global__ __launch_bounds__(1024) void permz_kernel(
    const float* __restrict__ z, const int* __restrict__ islot,
    unsigned short* __restrict__ zs)   // [B*M + slack][C] bf16
{
    const int t  = threadIdx.x;
    const int b  = blockIdx.x >> 7;
    const int m0 = (blockIdx.x & 127) * 64;
    __shared__ float tile[64][65];
    __shared__ int slot_s[64];

    const int m = t & 63;
    #pragma unroll
    for (int k = 0; k < 4; ++k) {
        int c = (t >> 6) + 16 * k;
        tile[c][m] = z[((size_t)b * C + c) * M + m0 + m];   // coalesced in m
    }
    if (t < 64) slot_s[t] = islot[b * M + m0 + t];
    __syncthreads();

    const int j  = t >> 4;
    const int c4 = t & 15;
    ushort4 v4;
    v4.x = f2bf(tile[c4 * 4 + 0][j]);
    v4.y = f2bf(tile[c4 * 4 + 1][j]);
    v4.z = f2bf(tile[c4 * 4 + 2][j]);
    v4.w = f2bf(tile[c4 * 4 + 3][j]);
    ((ushort4*)zs)[((size_t)b * M + slot_s[j]) * 16 + c4] = v4;
}

// One block per 16 sorted queries; 4 waves; mfma_f32_16x16x32_bf16.
// Weights computed ONCE per block (4 exp/lane) into padded LDS wl;
// A-fragments = ds_read_b128 from wl; 64-aligned windows -> no masking
// (extra slots are real points with true weights; reference sums all M).
__global__ __launch_bounds__(256) void gather_kernel(
    const float* __restrict__ log_scale,
    const int* __restrict__ bucket_start,
    const float* __restrict__ xs,
    const float* __restrict__ qcs,
    const int* __restrict__ qis,
    const unsigned short* __restrict__ zs,   // [B*M + slack][C] bf16
    float* __restrict__ out)                 // [B][N][C]
{
    const int t    = threadIdx.x;
    const int lane = t & 63;
    const int w    = t >> 6;            // wave 0..3 -> channels w*16..+15
    const int quad = lane >> 4;         // 0..3
    const int low4 = lane & 15;
    const int g  = blockIdx.x;
    const int b  = g >> 8;              // 256 groups per batch
    const int g0 = (g & 255) * QG;

    __shared__ unsigned short zr[64 * 64];   // 8 KB: 64 rows x 64 ch bf16
    __shared__ unsigned short wl[QG][72];    // 2.25 KB padded (144B rows)
    __shared__ float qcS[QG];
    __shared__ int   qiS[QG];

    const float ls   = log_scale[0];
    const float coef = -0.5f * __expf(-2.0f * ls);   // negative
    const float R    = sqrtf(CUT / (-coef));

    if (t < QG) {
        qcS[t] = qcs[b * N + g0 + t];
        qiS[t] = qis[b * N + g0 + t];
    }
    __syncthreads();

    float xmin = qcS[0], xmax = qcS[0];
    #pragma unroll
    for (int j = 1; j < QG; ++j) {
        xmin = fminf(xmin, qcS[j]);
        xmax = fmaxf(xmax, qcS[j]);
    }
    const int s0 = bucket_start[b * (NB + 1) + bucket_of(xmin - R)];
    const int s1 = bucket_start[b * (NB + 1) + bucket_of(xmax + R) + 1];
    const int e0 = s0 & ~63;                 // 64-aligned window; M%64==0
    const int e1 = (s1 + 63) & ~63;          // so [e0,e1) stays in [0,M]

    // weight-phase mapping: this lane computes queries qw, points pg*4..+3
    const int qw = w * 4 + (lane >> 4);      // 0..15
    const int pg = lane & 15;                // point group (x4)
    const float qv = qcS[qw];

    f32x4 acc = {0.f, 0.f, 0.f, 0.f};

    const float* xsb = xs + b * M;
    const unsigned short* zsb = zs + (size_t)b * M * C;

    for (int cs = e0; cs < e1; cs += 64) {
        __syncthreads();                 // zr/wl free from previous chunk
        // stage rows cs..cs+63 (128B bf16 rows): 2 global_load_lds per wave
        #pragma unroll
        for (int r = 0; r < 2; ++r) {
            const unsigned short* gp =
                zsb + ((size_t)cs + (w * 2 + r) * 8 + (lane >> 3)) * C + (lane & 7) * 8;
            unsigned short* lp = zr + (w * 2 + r) * 512;   // wave-uniform base
            __builtin_amdgcn_global_load_lds(
                (const __attribute__((address_space(1))) void*)gp,
                (__attribute__((address_space(3))) void*)lp, 16, 0, 0);
        }
        // block-shared weights (overlap the staging): 4 exp per lane
        {
            const float4 xp4 = *(const float4*)(xsb + cs + pg * 4);  // 16B-aligned
            float d0 = qv - xp4.x, d1 = qv - xp4.y;
            float d2 = qv - xp4.z, d3 = qv - xp4.w;
            ushort4 wv;
            wv.x = f2bf(__expf(coef * d0 * d0));
            wv.y = f2bf(__expf(coef * d1 * d1));
            wv.z = f2bf(__expf(coef * d2 * d2));
            wv.w = f2bf(__expf(coef * d3 * d3));
            *(ushort4*)&wl[qw][pg * 4] = wv;
        }
        __syncthreads();                 // zr staged + wl written
        // A = weights via b128 (padded rows), B = zr scalar u16, 2 MFMA
        #pragma unroll
        for (int kh = 0; kh < 2; ++kh) {
            short8 afrag = *(const short8*)&wl[low4][kh * 32 + quad * 8];
            short8 bfrag;
            #pragma unroll
            for (int j = 0; j < 8; ++j) {
                const int p = kh * 32 + quad * 8 + j;
                bfrag[j] = (short)zr[p * 64 + w * 16 + low4];
            }
            acc = __builtin_amdgcn_mfma_f32_16x16x32_bf16(afrag, bfrag, acc, 0, 0, 0);
        }
    }

    // D: row(query) = quad*4 + r, col(channel local) = low4
    #pragma unroll
    for (int r = 0; r < 4; ++r) {
        const int q = quad * 4 + r;
        out[((size_t)b * N + qiS[q]) * C + w * 16 + low4] = acc[r];
    }
}

extern "C" void kernel_launch(void* const* d_in, const int* in_sizes, int n_in,
                              void* d_out, int out_size, void* d_ws, size_t ws_size,
                              hipStream_t stream) {
    const float* xz = (const float*)d_in[0];  // [B,M,1]
    const float* z  = (const float*)d_in[1];  // [B,C,M]
    const float* x  = (const float*)d_in[2];  // [B,N,1]
    const float* ls = (const float*)d_in[3];  // scalar
    float* out = (float*)d_out;               // [B,N,C]

    char* ws = (char*)d_ws;
    size_t off = 0;
    auto alloc = [&](size_t bytes) { void* p = ws + off; off += (bytes + 255) & ~size_t(255); return p; };

    unsigned short* zs = (unsigned short*)alloc(((size_t)B * M + 64) * C * sizeof(unsigned short)); // ~4.2MB
    float* xs    = (float*)alloc(((size_t)B * M + 64) * sizeof(float));
    int*   islot = (int*)alloc((size_t)B * M * sizeof(int));
    float* qcs   = (float*)alloc((size_t)B * N * sizeof(float));
    int*   qis   = (int*)alloc((size_t)B * N * sizeof(int));
    int*   bst   = (int*)alloc((size_t)B * (NB + 1) * sizeof(int));

    bin_kernel<<<8, 1024, 0, stream>>>(xz, x, bst, xs, islot, qcs, qis);
    permz_kernel<<<512, 1024, 0, stream>>>(z, islot, zs);
    gather_kernel<<<B * (N / QG), 256, 0, stream>>>(ls, bst, xs, qcs, qis, zs, out);
}